// Round 1
// baseline (244.940 us; speedup 1.0000x reference)
//
#include <hip/hip_runtime.h>
#include <math.h>

#define D 128
#define BN_EPS 1e-3f
#define L2_EPS 1e-12f

typedef unsigned int uint;
typedef unsigned short ushort;
typedef __attribute__((ext_vector_type(8))) short bf16x8;  // 8 bf16 in 4 VGPRs
typedef __attribute__((ext_vector_type(4))) float f32x4;

__device__ __forceinline__ ushort f2bf(float f) {
  uint u = __float_as_uint(f);
  uint r = (u + 0x7fffu + ((u >> 16) & 1u)) >> 16;
  return (ushort)r;
}
__device__ __forceinline__ float bflo(uint u) { return __uint_as_float(u << 16); }
__device__ __forceinline__ float bfhi(uint u) { return __uint_as_float(u & 0xffff0000u); }
__device__ __forceinline__ float bf2f(ushort h) { return __uint_as_float(((uint)h) << 16); }

// ---------------------------------------------------------------------------
// Device helpers for the fused prep kernel
// ---------------------------------------------------------------------------
__device__ __forceinline__ void pack_bfrag_block(
    const float* __restrict__ W, const float* __restrict__ gamma,
    const float* __restrict__ var, ushort* __restrict__ Bf, int blk, int tid) {
  int t = blk * 256 + tid;  // 0..2047
  int f = t >> 6, lane = t & 63;
  int kc = f >> 3, nt = f & 7, q = lane >> 4, m = lane & 15;
  ushort tmp[8];
#pragma unroll
  for (int j = 0; j < 8; ++j) {
    int k = kc * 32 + q * 8 + j;
    float s = gamma[k] * rsqrtf(var[k] + BN_EPS);
    tmp[j] = f2bf(s * W[k * D + nt * 16 + m]);
  }
  uint4 o;
  o.x = (uint)tmp[0] | ((uint)tmp[1] << 16);
  o.y = (uint)tmp[2] | ((uint)tmp[3] << 16);
  o.z = (uint)tmp[4] | ((uint)tmp[5] << 16);
  o.w = (uint)tmp[6] | ((uint)tmp[7] << 16);
  reinterpret_cast<uint4*>(Bf)[t] = o;
}

__device__ __forceinline__ void bn_bias_block(
    const float* __restrict__ W, const float* __restrict__ gamma,
    const float* __restrict__ beta, const float* __restrict__ mean,
    const float* __restrict__ var, float* __restrict__ outb, int j) {
  float acc = 0.f;
  for (int k = 0; k < D; ++k) {
    float s = gamma[k] * rsqrtf(var[k] + BN_EPS);
    float sh = beta[k] - mean[k] * s;
    acc += sh * W[k * D + j];
  }
  outb[j] = acc;
}

// ---------------------------------------------------------------------------
// Fused prep: [0,nbConv) f32->bf16 | [+nbRp) row_ptr | +8 Bf1 | +8 Bf2 |
// +1 bnb | +1 shd | rest: packed edge arrays, COL-SORTED WITHIN EACH ROW:
//   ew1[s+rank]=(col,adj), ew2[s+rank]=(col, adj/(relc[rel]+1)).
// Sorting rationale: spmm gathers are LLC-bound (random 256B reads over a
// 12.8MB source that misses the 4MB per-XCD L2). Col-sorted edge lists make
// all concurrent waves sweep the source roughly in order -> active window
// of a few MB -> L2-resident gathers.
// Rank is computed stably per edge by scanning its row segment in the
// (sorted) rows[] array -- no dependency on row_ptr, stays one kernel.
// One pad entry (0,0) at index e.
// ---------------------------------------------------------------------------
__global__ __launch_bounds__(256) void prep_kernel(
    const float* __restrict__ x, ushort* __restrict__ xbf, int n4,
    const int* __restrict__ rows, int* __restrict__ row_ptr, int n, int e,
    const float* __restrict__ W1, const float* __restrict__ g1,
    const float* __restrict__ v1, ushort* __restrict__ Bf1,
    const float* __restrict__ Wd, const float* __restrict__ g2,
    const float* __restrict__ v2, ushort* __restrict__ Bf2,
    const float* __restrict__ beta1, const float* __restrict__ mean1,
    float* __restrict__ bnb,
    const float* __restrict__ beta2, const float* __restrict__ mean2,
    float* __restrict__ shd,
    const int* __restrict__ cols, const float* __restrict__ adj,
    const int* __restrict__ rel, const float* __restrict__ relc,
    uint2* __restrict__ ew1, uint2* __restrict__ ew2,
    int nbConv, int nbRp) {
  const int b = blockIdx.x, tid = threadIdx.x;
  if (b < nbConv) {
    int i = b * 256 + tid;
    if (i < n4) {
      float4 v = reinterpret_cast<const float4*>(x)[i];
      ushort4 o;
      o.x = f2bf(v.x); o.y = f2bf(v.y); o.z = f2bf(v.z); o.w = f2bf(v.w);
      reinterpret_cast<ushort4*>(xbf)[i] = o;
    }
    return;
  }
  int bb = b - nbConv;
  if (bb < nbRp) {
    int i = bb * 256 + tid;
    if (i <= n) {
      int lo = 0, hi = e;
      while (lo < hi) {
        int mid = (lo + hi) >> 1;
        if (rows[mid] < i) lo = mid + 1; else hi = mid;
      }
      row_ptr[i] = lo;
    }
    return;
  }
  bb -= nbRp;
  if (bb < 8) { pack_bfrag_block(W1, g1, v1, Bf1, bb, tid); return; }
  if (bb < 16) { pack_bfrag_block(Wd, g2, v2, Bf2, bb - 8, tid); return; }
  if (bb == 16) { if (tid < D) bn_bias_block(W1, g1, beta1, mean1, v1, bnb, tid); return; }
  if (bb == 17) { if (tid < D) bn_bias_block(Wd, g2, beta2, mean2, v2, shd, tid); return; }
  int i = (bb - 18) * 256 + tid;
  if (i < e) {
    const int r = rows[i];
    const uint c = (uint)cols[i];
    // Row segment bounds by local scan (rows[] is sorted; avg degree ~13).
    int s = i;
    while (s > 0 && rows[s - 1] == r) --s;
    int t = i + 1;
    while (t < e && rows[t] == r) ++t;
    // Stable rank of this edge's col within the row segment.
    int rank = 0;
    for (int k = s; k < t; ++k) {
      uint ck2 = (uint)cols[k];
      rank += (ck2 < c) || (ck2 == c && k < i);
    }
    const int o = s + rank;
    float a = adj[i];
    ew1[o] = make_uint2(c, __float_as_uint(a));
    float w2 = a / (relc[rel[i]] + 1.0f);
    ew2[o] = make_uint2(c, __float_as_uint(w2));
  } else if (i == e) {
    ew1[i] = make_uint2(0u, 0u);
    ew2[i] = make_uint2(0u, 0u);
  }
}

// ---------------------------------------------------------------------------
// SpMM (CSR pull): 4 rows per wave, 16 lanes per row, one uint4 (16 B = 8
// bf16) gather per lane per edge -> one dwordx4 instruction serves 4 edges.
// Edge meta from packed ew[] (col, weight), col-sorted within row so the
// gather sweep is roughly monotone across all concurrent waves.
// Masked slots clamp to last edge, weight 0 -> L1-hot re-read.
//   outA[r] = sum_e w_e * src[col_e]   (+ SELF: src[r]*(ck[r]+1)),  bf16 out.
//   rowsum[r] = sum_e w_e.
// ---------------------------------------------------------------------------
template <bool SELF>
__global__ __launch_bounds__(256) void spmm4_kernel(
    const ushort* __restrict__ src, const int* __restrict__ row_ptr,
    const uint2* __restrict__ ew, const float* __restrict__ ck,
    ushort* __restrict__ outA, float* __restrict__ rowsum, int n) {
  const int lane = threadIdx.x & 63;
  const int g = lane >> 4, m = lane & 15;
  const int r = blockIdx.x * 16 + (threadIdx.x >> 6) * 4 + g;
  const int rr = r < n ? r : n - 1;
  const int e0 = row_ptr[rr];
  int len = row_ptr[rr + 1] - e0;
  if (r >= n) len = 0;
  int mx = len;
  mx = max(mx, __shfl_xor(mx, 16));
  mx = max(mx, __shfl_xor(mx, 32));
  const int lastOff = len > 0 ? len - 1 : 0;

  const uint4* S4 = reinterpret_cast<const uint4*>(src);  // row stride 16
  float acc[8] = {0.f, 0.f, 0.f, 0.f, 0.f, 0.f, 0.f, 0.f};
  float ws = 0.f;

  for (int i = 0; i < mx; i += 4) {
    uint2 md[4];
    uint4 gv[4];
#pragma unroll
    for (int u = 0; u < 4; ++u) {
      int ii = i + u;
      int off = ii < len ? ii : lastOff;
      md[u] = ew[e0 + off];
    }
#pragma unroll
    for (int u = 0; u < 4; ++u) gv[u] = S4[(size_t)md[u].x * 16 + m];
#pragma unroll
    for (int u = 0; u < 4; ++u) {
      float w = (i + u) < len ? __uint_as_float(md[u].y) : 0.f;
      ws += w;
      acc[0] = fmaf(w, bflo(gv[u].x), acc[0]);
      acc[1] = fmaf(w, bfhi(gv[u].x), acc[1]);
      acc[2] = fmaf(w, bflo(gv[u].y), acc[2]);
      acc[3] = fmaf(w, bfhi(gv[u].y), acc[3]);
      acc[4] = fmaf(w, bflo(gv[u].z), acc[4]);
      acc[5] = fmaf(w, bfhi(gv[u].z), acc[5]);
      acc[6] = fmaf(w, bflo(gv[u].w), acc[6]);
      acc[7] = fmaf(w, bfhi(gv[u].w), acc[7]);
    }
  }

  if (r >= n) return;
  if (SELF) {
    uint4 us = S4[(size_t)rr * 16 + m];
    float cp = ck[rr] + 1.0f;
    acc[0] = fmaf(cp, bflo(us.x), acc[0]);
    acc[1] = fmaf(cp, bfhi(us.x), acc[1]);
    acc[2] = fmaf(cp, bflo(us.y), acc[2]);
    acc[3] = fmaf(cp, bfhi(us.y), acc[3]);
    acc[4] = fmaf(cp, bflo(us.z), acc[4]);
    acc[5] = fmaf(cp, bfhi(us.z), acc[5]);
    acc[6] = fmaf(cp, bflo(us.w), acc[6]);
    acc[7] = fmaf(cp, bfhi(us.w), acc[7]);
  }
  uint4 o;
  o.x = (uint)f2bf(acc[0]) | ((uint)f2bf(acc[1]) << 16);
  o.y = (uint)f2bf(acc[2]) | ((uint)f2bf(acc[3]) << 16);
  o.z = (uint)f2bf(acc[4]) | ((uint)f2bf(acc[5]) << 16);
  o.w = (uint)f2bf(acc[6]) | ((uint)f2bf(acc[7]) << 16);
  reinterpret_cast<uint4*>(outA)[(size_t)r * 16 + m] = o;
  if (m == 0) rowsum[r] = ws;
}

// ---------------------------------------------------------------------------
// GEMM1 (MFMA, no LDS, no barriers): y1 = tanh(A @ Ws + rs1*bnb + b1), bf16.
// ---------------------------------------------------------------------------
__global__ __launch_bounds__(256) void gemm1_mfma_kernel(
    const ushort* __restrict__ A, const ushort* __restrict__ Bf,
    const float* __restrict__ bnb, const float* __restrict__ b1,
    const float* __restrict__ rs1, ushort* __restrict__ y1, int M) {
  const int wave = threadIdx.x >> 6, lane = threadIdx.x & 63;
  const int row0 = blockIdx.x * 64 + wave * 16;
  if (row0 >= M) return;
  const int m = lane & 15, q = lane >> 4;
  const int row = row0 + m;
  const int arow = row < M ? row : M - 1;

  const bf16x8* Av = reinterpret_cast<const bf16x8*>(A);  // row stride: 16 frags
  const bf16x8* Bv = reinterpret_cast<const bf16x8*>(Bf);

  bf16x8 af[4];
#pragma unroll
  for (int kc = 0; kc < 4; ++kc) af[kc] = Av[(size_t)arow * 16 + kc * 4 + q];

  f32x4 acc[8];
#pragma unroll
  for (int nt = 0; nt < 8; ++nt) acc[nt] = (f32x4){0.f, 0.f, 0.f, 0.f};

#pragma unroll
  for (int kc = 0; kc < 4; ++kc) {
#pragma unroll
    for (int nt = 0; nt < 8; ++nt) {
      bf16x8 b = Bv[(kc * 8 + nt) * 64 + lane];
      acc[nt] = __builtin_amdgcn_mfma_f32_16x16x32_bf16(b, af[kc], acc[nt], 0, 0, 0);
    }
  }

  if (row < M) {
    float rs = rs1[row];
#pragma unroll
    for (int nt = 0; nt < 8; ++nt) {
      const float4 bn = *reinterpret_cast<const float4*>(&bnb[nt * 16 + q * 4]);
      const float4 bb = *reinterpret_cast<const float4*>(&b1[nt * 16 + q * 4]);
      ushort4 o;
      o.x = f2bf(tanhf(acc[nt][0] + rs * bn.x + bb.x));
      o.y = f2bf(tanhf(acc[nt][1] + rs * bn.y + bb.y));
      o.z = f2bf(tanhf(acc[nt][2] + rs * bn.z + bb.z));
      o.w = f2bf(tanhf(acc[nt][3] + rs * bn.w + bb.w));
      *reinterpret_cast<ushort4*>(&y1[(size_t)row * D + nt * 16 + q * 4]) = o;
    }
  }
}

// ---------------------------------------------------------------------------
// GEMM2 + finalize (fused): y2 = A2 @ Wds + (rs2+ck+1)*shd + bd, then
// out[r] = l2n([l2n(x_r), l2n(y1_r), l2n(y2_r)]).
// ---------------------------------------------------------------------------
__global__ __launch_bounds__(256) void gemm2_fused_kernel(
    const ushort* __restrict__ A2, const ushort* __restrict__ Bf,
    const float* __restrict__ shd, const float* __restrict__ bd,
    const float* __restrict__ rs2, const float* __restrict__ ck,
    const float* __restrict__ x, const ushort* __restrict__ y1,
    float* __restrict__ out, int M) {
  const int wave = threadIdx.x >> 6, lane = threadIdx.x & 63;
  const int row0 = blockIdx.x * 64 + wave * 16;
  if (row0 >= M) return;
  const int m = lane & 15, q = lane >> 4;
  const int row = row0 + m;
  const int arow = row < M ? row : M - 1;

  const bf16x8* Av = reinterpret_cast<const bf16x8*>(A2);
  const bf16x8* Bv = reinterpret_cast<const bf16x8*>(Bf);

  bf16x8 af[4];
#pragma unroll
  for (int kc = 0; kc < 4; ++kc) af[kc] = Av[(size_t)arow * 16 + kc * 4 + q];

  f32x4 acc[8];
#pragma unroll
  for (int nt = 0; nt < 8; ++nt) acc[nt] = (f32x4){0.f, 0.f, 0.f, 0.f};

#pragma unroll
  for (int kc = 0; kc < 4; ++kc) {
#pragma unroll
    for (int nt = 0; nt < 8; ++nt) {
      bf16x8 b = Bv[(kc * 8 + nt) * 64 + lane];
      acc[nt] = __builtin_amdgcn_mfma_f32_16x16x32_bf16(b, af[kc], acc[nt], 0, 0, 0);
    }
  }

  const float rb = rs2[arow] + ck[arow] + 1.0f;
  float4 xv[8];
  ushort4 y1v[8];
  float s0 = 0.f, s1 = 0.f, s2 = 0.f;
#pragma unroll
  for (int nt = 0; nt < 8; ++nt) {
    const float4 sh = *reinterpret_cast<const float4*>(&shd[nt * 16 + q * 4]);
    const float4 bb = *reinterpret_cast<const float4*>(&bd[nt * 16 + q * 4]);
    acc[nt][0] += rb * sh.x + bb.x;
    acc[nt][1] += rb * sh.y + bb.y;
    acc[nt][2] += rb * sh.z + bb.z;
    acc[nt][3] += rb * sh.w + bb.w;
    s2 += acc[nt][0] * acc[nt][0] + acc[nt][1] * acc[nt][1] +
          acc[nt][2] * acc[nt][2] + acc[nt][3] * acc[nt][3];
    xv[nt] = *reinterpret_cast<const float4*>(&x[(size_t)arow * D + nt * 16 + q * 4]);
    s0 += xv[nt].x * xv[nt].x + xv[nt].y * xv[nt].y +
          xv[nt].z * xv[nt].z + xv[nt].w * xv[nt].w;
    y1v[nt] = *reinterpret_cast<const ushort4*>(&y1[(size_t)arow * D + nt * 16 + q * 4]);
    float ya = bf2f(y1v[nt].x), yb = bf2f(y1v[nt].y);
    float yc = bf2f(y1v[nt].z), yd = bf2f(y1v[nt].w);
    s1 += ya * ya + yb * yb + yc * yc + yd * yd;
  }
  s0 += __shfl_xor(s0, 16); s0 += __shfl_xor(s0, 32);
  s1 += __shfl_xor(s1, 16); s1 += __shfl_xor(s1, 32);
  s2 += __shfl_xor(s2, 16); s2 += __shfl_xor(s2, 32);
  const float i0 = 1.0f / sqrtf(fmaxf(s0, L2_EPS));
  const float i1 = 1.0f / sqrtf(fmaxf(s1, L2_EPS));
  const float i2 = 1.0f / sqrtf(fmaxf(s2, L2_EPS));
  const float tot = s0 * i0 * i0 + s1 * i1 * i1 + s2 * i2 * i2;
  const float sc = 1.0f / sqrtf(fmaxf(tot, L2_EPS));
  const float f0 = i0 * sc, f1 = i1 * sc, f2 = i2 * sc;

  if (row < M) {
    float* orow = out + (size_t)row * 384;
#pragma unroll
    for (int nt = 0; nt < 8; ++nt) {
      const int c = nt * 16 + q * 4;
      float4 ox = make_float4(xv[nt].x * f0, xv[nt].y * f0, xv[nt].z * f0, xv[nt].w * f0);
      float4 oy = make_float4(bf2f(y1v[nt].x) * f1, bf2f(y1v[nt].y) * f1,
                              bf2f(y1v[nt].z) * f1, bf2f(y1v[nt].w) * f1);
      float4 oz = make_float4(acc[nt][0] * f2, acc[nt][1] * f2,
                              acc[nt][2] * f2, acc[nt][3] * f2);
      *reinterpret_cast<float4*>(orow + c) = ox;
      *reinterpret_cast<float4*>(orow + 128 + c) = oy;
      *reinterpret_cast<float4*>(orow + 256 + c) = oz;
    }
  }
}

// ---------------------------------------------------------------------------
extern "C" void kernel_launch(void* const* d_in, const int* in_sizes, int n_in,
                              void* d_out, int out_size, void* d_ws, size_t ws_size,
                              hipStream_t stream) {
  const float* x      = (const float*)d_in[0];
  const int*   rows   = (const int*)d_in[1];
  const int*   cols   = (const int*)d_in[2];
  const float* adj    = (const float*)d_in[3];
  const int*   rel    = (const int*)d_in[4];
  const float* gamma1 = (const float*)d_in[5];
  const float* beta1  = (const float*)d_in[6];
  const float* mean1  = (const float*)d_in[7];
  const float* var1   = (const float*)d_in[8];
  const float* W1     = (const float*)d_in[9];
  const float* b1     = (const float*)d_in[10];
  const float* gamma2 = (const float*)d_in[11];
  const float* beta2  = (const float*)d_in[12];
  const float* mean2  = (const float*)d_in[13];
  const float* var2   = (const float*)d_in[14];
  const float* relc   = (const float*)d_in[15];
  const float* ck     = (const float*)d_in[16];
  const float* Wd     = (const float*)d_in[17];
  const float* bd     = (const float*)d_in[18];
  float* out = (float*)d_out;

  const int n = in_sizes[0] / D;
  const int e = in_sizes[1];
  size_t nd = (size_t)n * D;

  char* p = (char*)d_ws;
  ushort* xbf   = (ushort*)p; p += nd * 2;
  ushort* y1bf  = (ushort*)p; p += nd * 2;
  ushort* aggbf = (ushort*)p; p += nd * 2;
  ushort* Bf1   = (ushort*)p; p += 32768;
  ushort* Bf2   = (ushort*)p; p += 32768;
  float*  bnb   = (float*)p;  p += 512;
  float*  shd   = (float*)p;  p += 512;
  float*  rs1   = (float*)p;  p += (size_t)n * 4;
  float*  rs2   = (float*)p;  p += (size_t)n * 4;
  p = (char*)(((uintptr_t)p + 15) & ~(uintptr_t)15);
  uint2* ew1    = (uint2*)p;  p += (size_t)(e + 1) * 8;
  uint2* ew2    = (uint2*)p;  p += (size_t)(e + 1) * 8;
  int* row_ptr  = (int*)p;    p += (size_t)(n + 1) * 4;

  const int n4 = (int)(nd / 4);
  const int nbConv = (n4 + 255) / 256;
  const int nbRp = (n + 1 + 255) / 256;
  const int nbEw = (e + 1 + 255) / 256;
  const int nbPrep = nbConv + nbRp + 18 + nbEw;

  prep_kernel<<<nbPrep, 256, 0, stream>>>(
      x, xbf, n4, rows, row_ptr, n, e,
      W1, gamma1, var1, Bf1, Wd, gamma2, var2, Bf2,
      beta1, mean1, bnb, beta2, mean2, shd,
      cols, adj, rel, relc, ew1, ew2, nbConv, nbRp);

  int sblocks = (n + 15) / 16;
  int gblocks = (n + 63) / 64;

  spmm4_kernel<false><<<sblocks, 256, 0, stream>>>(
      xbf, row_ptr, ew1, nullptr, aggbf, rs1, n);
  gemm1_mfma_kernel<<<gblocks, 256, 0, stream>>>(aggbf, Bf1, bnb, b1, rs1, y1bf, n);
  spmm4_kernel<true><<<sblocks, 256, 0, stream>>>(
      y1bf, row_ptr, ew2, ck, aggbf, rs2, n);
  gemm2_fused_kernel<<<gblocks, 256, 0, stream>>>(
      aggbf, Bf2, shd, bd, rs2, ck, x, y1bf, out, n);
}

// Round 2
// 214.337 us; speedup vs baseline: 1.1428x; 1.1428x over previous
//
#include <hip/hip_runtime.h>
#include <math.h>

#define D 128
#define BN_EPS 1e-3f
#define L2_EPS 1e-12f
#define AGG_S 136  // ushort stride for 16x128 bf16 LDS tile (+8 pad => bank spread)
#define OUT_S 392  // float stride for 16x384 f32 out tile (+8 pad, 16B aligned)

typedef unsigned int uint;
typedef unsigned short ushort;
typedef __attribute__((ext_vector_type(8))) short bf16x8;  // 8 bf16 in 4 VGPRs
typedef __attribute__((ext_vector_type(4))) float f32x4;

__device__ __forceinline__ ushort f2bf(float f) {
  uint u = __float_as_uint(f);
  uint r = (u + 0x7fffu + ((u >> 16) & 1u)) >> 16;
  return (ushort)r;
}
__device__ __forceinline__ float bflo(uint u) { return __uint_as_float(u << 16); }
__device__ __forceinline__ float bfhi(uint u) { return __uint_as_float(u & 0xffff0000u); }
__device__ __forceinline__ float bf2f(ushort h) { return __uint_as_float(((uint)h) << 16); }

// ---------------------------------------------------------------------------
// Device helpers for the fused prep kernel
// ---------------------------------------------------------------------------
__device__ __forceinline__ void pack_bfrag_block(
    const float* __restrict__ W, const float* __restrict__ gamma,
    const float* __restrict__ var, ushort* __restrict__ Bf, int blk, int tid) {
  int t = blk * 256 + tid;  // 0..2047
  int f = t >> 6, lane = t & 63;
  int kc = f >> 3, nt = f & 7, q = lane >> 4, m = lane & 15;
  ushort tmp[8];
#pragma unroll
  for (int j = 0; j < 8; ++j) {
    int k = kc * 32 + q * 8 + j;
    float s = gamma[k] * rsqrtf(var[k] + BN_EPS);
    tmp[j] = f2bf(s * W[k * D + nt * 16 + m]);
  }
  uint4 o;
  o.x = (uint)tmp[0] | ((uint)tmp[1] << 16);
  o.y = (uint)tmp[2] | ((uint)tmp[3] << 16);
  o.z = (uint)tmp[4] | ((uint)tmp[5] << 16);
  o.w = (uint)tmp[6] | ((uint)tmp[7] << 16);
  reinterpret_cast<uint4*>(Bf)[t] = o;
}

__device__ __forceinline__ void bn_bias_block(
    const float* __restrict__ W, const float* __restrict__ gamma,
    const float* __restrict__ beta, const float* __restrict__ mean,
    const float* __restrict__ var, float* __restrict__ outb, int j) {
  float acc = 0.f;
  for (int k = 0; k < D; ++k) {
    float s = gamma[k] * rsqrtf(var[k] + BN_EPS);
    float sh = beta[k] - mean[k] * s;
    acc += sh * W[k * D + j];
  }
  outb[j] = acc;
}

// ---------------------------------------------------------------------------
// Fused prep: [0,nbConv) f32->bf16 | [+nbRp) row_ptr | +8 Bf1 | +8 Bf2 |
// +1 bnb | +1 shd | rest: packed edge arrays ew1=(col,adj),
// ew2=(col, adj/(relc[rel]+1)), one pad entry (0,0) at index e.
// (Round-1 col-sort reverted: grid is fully resident so per-row order cannot
// shrink the gather working set; the rank scan cost +13.5us for 0 benefit.)
// ---------------------------------------------------------------------------
__global__ __launch_bounds__(256) void prep_kernel(
    const float* __restrict__ x, ushort* __restrict__ xbf, int n4,
    const int* __restrict__ rows, int* __restrict__ row_ptr, int n, int e,
    const float* __restrict__ W1, const float* __restrict__ g1,
    const float* __restrict__ v1, ushort* __restrict__ Bf1,
    const float* __restrict__ Wd, const float* __restrict__ g2,
    const float* __restrict__ v2, ushort* __restrict__ Bf2,
    const float* __restrict__ beta1, const float* __restrict__ mean1,
    float* __restrict__ bnb,
    const float* __restrict__ beta2, const float* __restrict__ mean2,
    float* __restrict__ shd,
    const int* __restrict__ cols, const float* __restrict__ adj,
    const int* __restrict__ rel, const float* __restrict__ relc,
    uint2* __restrict__ ew1, uint2* __restrict__ ew2,
    int nbConv, int nbRp) {
  const int b = blockIdx.x, tid = threadIdx.x;
  if (b < nbConv) {
    int i = b * 256 + tid;
    if (i < n4) {
      float4 v = reinterpret_cast<const float4*>(x)[i];
      ushort4 o;
      o.x = f2bf(v.x); o.y = f2bf(v.y); o.z = f2bf(v.z); o.w = f2bf(v.w);
      reinterpret_cast<ushort4*>(xbf)[i] = o;
    }
    return;
  }
  int bb = b - nbConv;
  if (bb < nbRp) {
    int i = bb * 256 + tid;
    if (i <= n) {
      int lo = 0, hi = e;
      while (lo < hi) {
        int mid = (lo + hi) >> 1;
        if (rows[mid] < i) lo = mid + 1; else hi = mid;
      }
      row_ptr[i] = lo;
    }
    return;
  }
  bb -= nbRp;
  if (bb < 8) { pack_bfrag_block(W1, g1, v1, Bf1, bb, tid); return; }
  if (bb < 16) { pack_bfrag_block(Wd, g2, v2, Bf2, bb - 8, tid); return; }
  if (bb == 16) { if (tid < D) bn_bias_block(W1, g1, beta1, mean1, v1, bnb, tid); return; }
  if (bb == 17) { if (tid < D) bn_bias_block(Wd, g2, beta2, mean2, v2, shd, tid); return; }
  int i = (bb - 18) * 256 + tid;
  if (i < e) {
    uint c = (uint)cols[i];
    float a = adj[i];
    ew1[i] = make_uint2(c, __float_as_uint(a));
    float w2 = a / (relc[rel[i]] + 1.0f);
    ew2[i] = make_uint2(c, __float_as_uint(w2));
  } else if (i == e) {
    ew1[i] = make_uint2(0u, 0u);
    ew2[i] = make_uint2(0u, 0u);
  }
}

// ---------------------------------------------------------------------------
// SpMM phase (CSR pull): 4 rows per wave, 16 lanes per row, one uint4 (16 B
// = 8 bf16) gather per lane per edge. Returns rowsum; acc[8] = f32 partials
// for cols m*8..m*8+7. No early returns (callers have barriers after).
// ---------------------------------------------------------------------------
template <bool SELF>
__device__ __forceinline__ float spmm_rows(
    const uint4* __restrict__ S4, const int* __restrict__ row_ptr,
    const uint2* __restrict__ ew, const float* __restrict__ ck,
    int r, int n, int m, float acc[8]) {
  const int rr = r < n ? r : n - 1;
  const int e0 = row_ptr[rr];
  int len = row_ptr[rr + 1] - e0;
  if (r >= n) len = 0;
  int mx = len;
  mx = max(mx, __shfl_xor(mx, 16));
  mx = max(mx, __shfl_xor(mx, 32));
  const int lastOff = len > 0 ? len - 1 : 0;

#pragma unroll
  for (int j = 0; j < 8; ++j) acc[j] = 0.f;
  float ws = 0.f;

  for (int i = 0; i < mx; i += 4) {
    uint2 md[4];
    uint4 gv[4];
#pragma unroll
    for (int u = 0; u < 4; ++u) {
      int ii = i + u;
      int off = ii < len ? ii : lastOff;
      md[u] = ew[e0 + off];
    }
#pragma unroll
    for (int u = 0; u < 4; ++u) gv[u] = S4[(size_t)md[u].x * 16 + m];
#pragma unroll
    for (int u = 0; u < 4; ++u) {
      float w = (i + u) < len ? __uint_as_float(md[u].y) : 0.f;
      ws += w;
      acc[0] = fmaf(w, bflo(gv[u].x), acc[0]);
      acc[1] = fmaf(w, bfhi(gv[u].x), acc[1]);
      acc[2] = fmaf(w, bflo(gv[u].y), acc[2]);
      acc[3] = fmaf(w, bfhi(gv[u].y), acc[3]);
      acc[4] = fmaf(w, bflo(gv[u].z), acc[4]);
      acc[5] = fmaf(w, bfhi(gv[u].z), acc[5]);
      acc[6] = fmaf(w, bflo(gv[u].w), acc[6]);
      acc[7] = fmaf(w, bfhi(gv[u].w), acc[7]);
    }
  }

  if (SELF && r < n) {
    uint4 us = S4[(size_t)rr * 16 + m];
    float cp = ck[rr] + 1.0f;
    acc[0] = fmaf(cp, bflo(us.x), acc[0]);
    acc[1] = fmaf(cp, bfhi(us.x), acc[1]);
    acc[2] = fmaf(cp, bflo(us.y), acc[2]);
    acc[3] = fmaf(cp, bfhi(us.y), acc[3]);
    acc[4] = fmaf(cp, bflo(us.z), acc[4]);
    acc[5] = fmaf(cp, bfhi(us.z), acc[5]);
    acc[6] = fmaf(cp, bflo(us.w), acc[6]);
    acc[7] = fmaf(cp, bfhi(us.w), acc[7]);
  }
  return ws;
}

__device__ __forceinline__ uint4 pack_acc(const float acc[8]) {
  uint4 o;
  o.x = (uint)f2bf(acc[0]) | ((uint)f2bf(acc[1]) << 16);
  o.y = (uint)f2bf(acc[2]) | ((uint)f2bf(acc[3]) << 16);
  o.z = (uint)f2bf(acc[4]) | ((uint)f2bf(acc[5]) << 16);
  o.w = (uint)f2bf(acc[6]) | ((uint)f2bf(acc[7]) << 16);
  return o;
}

// ---------------------------------------------------------------------------
// Fused K2: spmm1 (16 rows/block via LDS) + GEMM1 + tanh, LDS-staged
// coalesced y1 writes. Saves the aggbf/rs1 global round trip.
// ---------------------------------------------------------------------------
__global__ __launch_bounds__(256) void spmm_gemm1_kernel(
    const ushort* __restrict__ src, const int* __restrict__ row_ptr,
    const uint2* __restrict__ ew, const ushort* __restrict__ Bf,
    const float* __restrict__ bnb, const float* __restrict__ b1,
    ushort* __restrict__ y1, int n) {
  __shared__ ushort aggT[16 * AGG_S];
  __shared__ ushort y1T[16 * AGG_S];
  __shared__ float rsL[16];

  const int tid = threadIdx.x;
  const int wave = tid >> 6, lane = tid & 63;
  const int g = lane >> 4, m = lane & 15;
  const int rloc = wave * 4 + g;
  const int r = blockIdx.x * 16 + rloc;

  // ---- phase A: spmm into registers, stage bf16 tile in LDS ----
  float acc[8];
  float ws = spmm_rows<false>(reinterpret_cast<const uint4*>(src), row_ptr,
                              ew, nullptr, r, n, m, acc);
  *reinterpret_cast<uint4*>(&aggT[rloc * AGG_S + m * 8]) = pack_acc(acc);
  if (m == 0) rsL[rloc] = ws;
  __syncthreads();

  // ---- phase B: 16x128 @ 128x128 MFMA; wave handles nt = {2w, 2w+1} ----
  const bf16x8* Bv = reinterpret_cast<const bf16x8*>(Bf);
  bf16x8 af[4];
#pragma unroll
  for (int kc = 0; kc < 4; ++kc)
    af[kc] = *reinterpret_cast<const bf16x8*>(&aggT[m * AGG_S + kc * 32 + g * 8]);

  f32x4 acc2[2];
  acc2[0] = (f32x4){0.f, 0.f, 0.f, 0.f};
  acc2[1] = (f32x4){0.f, 0.f, 0.f, 0.f};
  const int nt0 = wave * 2;
#pragma unroll
  for (int kc = 0; kc < 4; ++kc) {
#pragma unroll
    for (int t = 0; t < 2; ++t) {
      bf16x8 b = Bv[(kc * 8 + nt0 + t) * 64 + lane];
      acc2[t] = __builtin_amdgcn_mfma_f32_16x16x32_bf16(b, af[kc], acc2[t], 0, 0, 0);
    }
  }

  const float rs = rsL[m];
#pragma unroll
  for (int t = 0; t < 2; ++t) {
    const int c = (nt0 + t) * 16 + g * 4;
    const float4 bn = *reinterpret_cast<const float4*>(&bnb[c]);
    const float4 bb = *reinterpret_cast<const float4*>(&b1[c]);
    ushort4 ov;
    ov.x = f2bf(tanhf(acc2[t][0] + rs * bn.x + bb.x));
    ov.y = f2bf(tanhf(acc2[t][1] + rs * bn.y + bb.y));
    ov.z = f2bf(tanhf(acc2[t][2] + rs * bn.z + bb.z));
    ov.w = f2bf(tanhf(acc2[t][3] + rs * bn.w + bb.w));
    *reinterpret_cast<ushort4*>(&y1T[m * AGG_S + c]) = ov;
  }
  __syncthreads();

  // ---- coalesced copy: 16 rows x 256 B = 4 KB, 1 uint4 per thread ----
  const int row = tid >> 4, col = tid & 15;
  uint4 v = *reinterpret_cast<const uint4*>(&y1T[row * AGG_S + col * 8]);
  const size_t gi = (size_t)blockIdx.x * 256 + tid;
  if ((int)(gi >> 4) < n) reinterpret_cast<uint4*>(y1)[gi] = v;
}

// ---------------------------------------------------------------------------
// Fused K3: spmm2(+self) + GEMM2 + bias + tri-L2-normalize + coalesced out.
// Cross-wave row norms via LDS partials; out staged in LDS (aliased over
// aggT: all aggT reads complete before the sp-barrier) and streamed out as
// linear float4 (1 KB/instr) instead of 16 B stores at 1536 B stride.
// ---------------------------------------------------------------------------
__global__ __launch_bounds__(256) void spmm_gemm2_kernel(
    const ushort* __restrict__ src /*y1bf*/, const int* __restrict__ row_ptr,
    const uint2* __restrict__ ew, const ushort* __restrict__ Bf,
    const float* __restrict__ shd, const float* __restrict__ bd,
    const float* __restrict__ ck, const float* __restrict__ x,
    float* __restrict__ out, int n) {
  __shared__ __align__(16) char smemRaw[16 * OUT_S * 4];  // outT / aggT alias
  __shared__ float rsL[16];
  __shared__ float sp0[4][16], sp1[4][16], sp2[4][16];
  ushort* aggT = reinterpret_cast<ushort*>(smemRaw);
  float* outT = reinterpret_cast<float*>(smemRaw);

  const int tid = threadIdx.x;
  const int wave = tid >> 6, lane = tid & 63;
  const int g = lane >> 4, m = lane & 15;
  const int rloc = wave * 4 + g;
  const int r = blockIdx.x * 16 + rloc;

  // ---- phase A: spmm with self term ----
  float acc[8];
  float ws = spmm_rows<true>(reinterpret_cast<const uint4*>(src), row_ptr,
                             ew, ck, r, n, m, acc);
  *reinterpret_cast<uint4*>(&aggT[rloc * AGG_S + m * 8]) = pack_acc(acc);
  if (m == 0) rsL[rloc] = ws;
  __syncthreads();

  // ---- phase B: GEMM; lane (g,m) owns row m, cols {nt0,nt0+1}*16+g*4 ----
  const bf16x8* Bv = reinterpret_cast<const bf16x8*>(Bf);
  bf16x8 af[4];
#pragma unroll
  for (int kc = 0; kc < 4; ++kc)
    af[kc] = *reinterpret_cast<const bf16x8*>(&aggT[m * AGG_S + kc * 32 + g * 8]);

  f32x4 acc2[2];
  acc2[0] = (f32x4){0.f, 0.f, 0.f, 0.f};
  acc2[1] = (f32x4){0.f, 0.f, 0.f, 0.f};
  const int nt0 = wave * 2;
#pragma unroll
  for (int kc = 0; kc < 4; ++kc) {
#pragma unroll
    for (int t = 0; t < 2; ++t) {
      bf16x8 b = Bv[(kc * 8 + nt0 + t) * 64 + lane];
      acc2[t] = __builtin_amdgcn_mfma_f32_16x16x32_bf16(b, af[kc], acc2[t], 0, 0, 0);
    }
  }

  // x / y1 col-slices: wave w covers cols w*32..w*32+31 of every row.
  const int rm = min(blockIdx.x * 16 + m, n - 1);
  const int c0 = wave * 32 + g * 8;
  const float4 xv0 = *reinterpret_cast<const float4*>(&x[(size_t)rm * D + c0]);
  const float4 xv1 = *reinterpret_cast<const float4*>(&x[(size_t)rm * D + c0 + 4]);
  const uint4 yv = *reinterpret_cast<const uint4*>(&src[(size_t)rm * D + c0]);
  const float ya = bflo(yv.x), yb = bfhi(yv.x), yc = bflo(yv.y), yd = bfhi(yv.y);
  const float ye = bflo(yv.z), yf = bfhi(yv.z), yg = bflo(yv.w), yh = bfhi(yv.w);

  float s0p = xv0.x * xv0.x + xv0.y * xv0.y + xv0.z * xv0.z + xv0.w * xv0.w +
              xv1.x * xv1.x + xv1.y * xv1.y + xv1.z * xv1.z + xv1.w * xv1.w;
  float s1p = ya * ya + yb * yb + yc * yc + yd * yd +
              ye * ye + yf * yf + yg * yg + yh * yh;

  const float rbias = rsL[m] + ck[rm] + 1.0f;
  float s2p = 0.f;
#pragma unroll
  for (int t = 0; t < 2; ++t) {
    const int c = (nt0 + t) * 16 + g * 4;
    const float4 sh = *reinterpret_cast<const float4*>(&shd[c]);
    const float4 bb = *reinterpret_cast<const float4*>(&bd[c]);
    acc2[t][0] += rbias * sh.x + bb.x;
    acc2[t][1] += rbias * sh.y + bb.y;
    acc2[t][2] += rbias * sh.z + bb.z;
    acc2[t][3] += rbias * sh.w + bb.w;
    s2p += acc2[t][0] * acc2[t][0] + acc2[t][1] * acc2[t][1] +
           acc2[t][2] * acc2[t][2] + acc2[t][3] * acc2[t][3];
  }

  // reduce over the 4 g-groups (same row m) within the wave
  s0p += __shfl_xor(s0p, 16); s0p += __shfl_xor(s0p, 32);
  s1p += __shfl_xor(s1p, 16); s1p += __shfl_xor(s1p, 32);
  s2p += __shfl_xor(s2p, 16); s2p += __shfl_xor(s2p, 32);
  if (lane < 16) { sp0[wave][lane] = s0p; sp1[wave][lane] = s1p; sp2[wave][lane] = s2p; }
  __syncthreads();  // also separates all aggT reads from outT writes (alias)

  const float s0 = sp0[0][m] + sp0[1][m] + sp0[2][m] + sp0[3][m];
  const float s1 = sp1[0][m] + sp1[1][m] + sp1[2][m] + sp1[3][m];
  const float s2 = sp2[0][m] + sp2[1][m] + sp2[2][m] + sp2[3][m];
  const float i0 = 1.0f / sqrtf(fmaxf(s0, L2_EPS));
  const float i1 = 1.0f / sqrtf(fmaxf(s1, L2_EPS));
  const float i2 = 1.0f / sqrtf(fmaxf(s2, L2_EPS));
  const float tot = s0 * i0 * i0 + s1 * i1 * i1 + s2 * i2 * i2;
  const float sc = 1.0f / sqrtf(fmaxf(tot, L2_EPS));
  const float f0 = i0 * sc, f1 = i1 * sc, f2 = i2 * sc;

  // ---- stage normalized row into outT ----
  float* orow = &outT[m * OUT_S];
  *reinterpret_cast<float4*>(&orow[c0]) =
      make_float4(xv0.x * f0, xv0.y * f0, xv0.z * f0, xv0.w * f0);
  *reinterpret_cast<float4*>(&orow[c0 + 4]) =
      make_float4(xv1.x * f0, xv1.y * f0, xv1.z * f0, xv1.w * f0);
  *reinterpret_cast<float4*>(&orow[128 + c0]) =
      make_float4(ya * f1, yb * f1, yc * f1, yd * f1);
  *reinterpret_cast<float4*>(&orow[128 + c0 + 4]) =
      make_float4(ye * f1, yf * f1, yg * f1, yh * f1);
#pragma unroll
  for (int t = 0; t < 2; ++t) {
    const int c = (nt0 + t) * 16 + g * 4;
    *reinterpret_cast<float4*>(&orow[256 + c]) =
        make_float4(acc2[t][0] * f2, acc2[t][1] * f2, acc2[t][2] * f2, acc2[t][3] * f2);
  }
  __syncthreads();

  // ---- coalesced copy: 16 rows x 1536 B; 6 x (256 threads x float4) ----
#pragma unroll
  for (int it = 0; it < 6; ++it) {
    const int idx = it * 256 + tid;        // 0..1535
    const int rw = idx / 96, cc = idx % 96;
    float4 v = *reinterpret_cast<const float4*>(&outT[rw * OUT_S + cc * 4]);
    const int gr = blockIdx.x * 16 + rw;
    if (gr < n) reinterpret_cast<float4*>(out)[(size_t)gr * 96 + cc] = v;
  }
}

// ---------------------------------------------------------------------------
extern "C" void kernel_launch(void* const* d_in, const int* in_sizes, int n_in,
                              void* d_out, int out_size, void* d_ws, size_t ws_size,
                              hipStream_t stream) {
  const float* x      = (const float*)d_in[0];
  const int*   rows   = (const int*)d_in[1];
  const int*   cols   = (const int*)d_in[2];
  const float* adj    = (const float*)d_in[3];
  const int*   rel    = (const int*)d_in[4];
  const float* gamma1 = (const float*)d_in[5];
  const float* beta1  = (const float*)d_in[6];
  const float* mean1  = (const float*)d_in[7];
  const float* var1   = (const float*)d_in[8];
  const float* W1     = (const float*)d_in[9];
  const float* b1     = (const float*)d_in[10];
  const float* gamma2 = (const float*)d_in[11];
  const float* beta2  = (const float*)d_in[12];
  const float* mean2  = (const float*)d_in[13];
  const float* var2   = (const float*)d_in[14];
  const float* relc   = (const float*)d_in[15];
  const float* ck     = (const float*)d_in[16];
  const float* Wd     = (const float*)d_in[17];
  const float* bd     = (const float*)d_in[18];
  float* out = (float*)d_out;

  const int n = in_sizes[0] / D;
  const int e = in_sizes[1];
  size_t nd = (size_t)n * D;

  char* p = (char*)d_ws;
  ushort* xbf   = (ushort*)p; p += nd * 2;
  ushort* y1bf  = (ushort*)p; p += nd * 2;
  ushort* Bf1   = (ushort*)p; p += 32768;
  ushort* Bf2   = (ushort*)p; p += 32768;
  float*  bnb   = (float*)p;  p += 512;
  float*  shd   = (float*)p;  p += 512;
  p = (char*)(((uintptr_t)p + 15) & ~(uintptr_t)15);
  uint2* ew1    = (uint2*)p;  p += (size_t)(e + 1) * 8;
  uint2* ew2    = (uint2*)p;  p += (size_t)(e + 1) * 8;
  int* row_ptr  = (int*)p;    p += (size_t)(n + 1) * 4;

  const int n4 = (int)(nd / 4);
  const int nbConv = (n4 + 255) / 256;
  const int nbRp = (n + 1 + 255) / 256;
  const int nbEw = (e + 1 + 255) / 256;
  const int nbPrep = nbConv + nbRp + 18 + nbEw;

  prep_kernel<<<nbPrep, 256, 0, stream>>>(
      x, xbf, n4, rows, row_ptr, n, e,
      W1, gamma1, var1, Bf1, Wd, gamma2, var2, Bf2,
      beta1, mean1, bnb, beta2, mean2, shd,
      cols, adj, rel, relc, ew1, ew2, nbConv, nbRp);

  const int fblocks = (n + 15) / 16;
  spmm_gemm1_kernel<<<fblocks, 256, 0, stream>>>(
      xbf, row_ptr, ew1, Bf1, bnb, b1, y1bf, n);
  spmm_gemm2_kernel<<<fblocks, 256, 0, stream>>>(
      y1bf, row_ptr, ew2, Bf2, shd, bd, ck, x, out, n);
}

// Round 3
// 213.839 us; speedup vs baseline: 1.1454x; 1.0023x over previous
//
#include <hip/hip_runtime.h>
#include <math.h>

#define D 128
#define BN_EPS 1e-3f
#define L2_EPS 1e-12f
#define AGG_S 136  // ushort stride for 16x128 bf16 LDS tile (+8 pad => bank spread)
#define OUT_S 392  // float stride for 16x384 f32 out tile (+8 pad, 16B aligned)

typedef unsigned int uint;
typedef unsigned short ushort;
typedef __attribute__((ext_vector_type(8))) short bf16x8;  // 8 bf16 in 4 VGPRs
typedef __attribute__((ext_vector_type(4))) float f32x4;

__device__ __forceinline__ ushort f2bf(float f) {
  uint u = __float_as_uint(f);
  uint r = (u + 0x7fffu + ((u >> 16) & 1u)) >> 16;
  return (ushort)r;
}
__device__ __forceinline__ float bflo(uint u) { return __uint_as_float(u << 16); }
__device__ __forceinline__ float bfhi(uint u) { return __uint_as_float(u & 0xffff0000u); }
__device__ __forceinline__ float bf2f(ushort h) { return __uint_as_float(((uint)h) << 16); }

// ---------------------------------------------------------------------------
// Device helpers for the fused prep kernel
// ---------------------------------------------------------------------------
__device__ __forceinline__ void pack_bfrag_block(
    const float* __restrict__ W, const float* __restrict__ gamma,
    const float* __restrict__ var, ushort* __restrict__ Bf, int blk, int tid) {
  int t = blk * 256 + tid;  // 0..2047
  int f = t >> 6, lane = t & 63;
  int kc = f >> 3, nt = f & 7, q = lane >> 4, m = lane & 15;
  ushort tmp[8];
#pragma unroll
  for (int j = 0; j < 8; ++j) {
    int k = kc * 32 + q * 8 + j;
    float s = gamma[k] * rsqrtf(var[k] + BN_EPS);
    tmp[j] = f2bf(s * W[k * D + nt * 16 + m]);
  }
  uint4 o;
  o.x = (uint)tmp[0] | ((uint)tmp[1] << 16);
  o.y = (uint)tmp[2] | ((uint)tmp[3] << 16);
  o.z = (uint)tmp[4] | ((uint)tmp[5] << 16);
  o.w = (uint)tmp[6] | ((uint)tmp[7] << 16);
  reinterpret_cast<uint4*>(Bf)[t] = o;
}

__device__ __forceinline__ void bn_bias_block(
    const float* __restrict__ W, const float* __restrict__ gamma,
    const float* __restrict__ beta, const float* __restrict__ mean,
    const float* __restrict__ var, float* __restrict__ outb, int j) {
  float acc = 0.f;
  for (int k = 0; k < D; ++k) {
    float s = gamma[k] * rsqrtf(var[k] + BN_EPS);
    float sh = beta[k] - mean[k] * s;
    acc += sh * W[k * D + j];
  }
  outb[j] = acc;
}

// ---------------------------------------------------------------------------
// Fused prep: [0,nbConv) f32->bf16 | [+nbRp) row_ptr | +8 Bf1 | +8 Bf2 |
// +1 bnb | +1 shd | rest: packed edge arrays ew1=(col,adj),
// ew2=(col, adj/(relc[rel]+1)), one pad entry (0,0) at index e.
// ---------------------------------------------------------------------------
__global__ __launch_bounds__(256) void prep_kernel(
    const float* __restrict__ x, ushort* __restrict__ xbf, int n4,
    const int* __restrict__ rows, int* __restrict__ row_ptr, int n, int e,
    const float* __restrict__ W1, const float* __restrict__ g1,
    const float* __restrict__ v1, ushort* __restrict__ Bf1,
    const float* __restrict__ Wd, const float* __restrict__ g2,
    const float* __restrict__ v2, ushort* __restrict__ Bf2,
    const float* __restrict__ beta1, const float* __restrict__ mean1,
    float* __restrict__ bnb,
    const float* __restrict__ beta2, const float* __restrict__ mean2,
    float* __restrict__ shd,
    const int* __restrict__ cols, const float* __restrict__ adj,
    const int* __restrict__ rel, const float* __restrict__ relc,
    uint2* __restrict__ ew1, uint2* __restrict__ ew2,
    int nbConv, int nbRp) {
  const int b = blockIdx.x, tid = threadIdx.x;
  if (b < nbConv) {
    int i = b * 256 + tid;
    if (i < n4) {
      float4 v = reinterpret_cast<const float4*>(x)[i];
      ushort4 o;
      o.x = f2bf(v.x); o.y = f2bf(v.y); o.z = f2bf(v.z); o.w = f2bf(v.w);
      reinterpret_cast<ushort4*>(xbf)[i] = o;
    }
    return;
  }
  int bb = b - nbConv;
  if (bb < nbRp) {
    int i = bb * 256 + tid;
    if (i <= n) {
      int lo = 0, hi = e;
      while (lo < hi) {
        int mid = (lo + hi) >> 1;
        if (rows[mid] < i) lo = mid + 1; else hi = mid;
      }
      row_ptr[i] = lo;
    }
    return;
  }
  bb -= nbRp;
  if (bb < 8) { pack_bfrag_block(W1, g1, v1, Bf1, bb, tid); return; }
  if (bb < 16) { pack_bfrag_block(Wd, g2, v2, Bf2, bb - 8, tid); return; }
  if (bb == 16) { if (tid < D) bn_bias_block(W1, g1, beta1, mean1, v1, bnb, tid); return; }
  if (bb == 17) { if (tid < D) bn_bias_block(Wd, g2, beta2, mean2, v2, shd, tid); return; }
  int i = (bb - 18) * 256 + tid;
  if (i < e) {
    uint c = (uint)cols[i];
    float a = adj[i];
    ew1[i] = make_uint2(c, __float_as_uint(a));
    float w2 = a / (relc[rel[i]] + 1.0f);
    ew2[i] = make_uint2(c, __float_as_uint(w2));
  } else if (i == e) {
    ew1[i] = make_uint2(0u, 0u);
    ew2[i] = make_uint2(0u, 0u);
  }
}

// ---------------------------------------------------------------------------
// SpMM phase (CSR pull): 4 rows per wave, 16 lanes per row. Edge metas for a
// 16-edge chunk are loaded COOPERATIVELY (lane m -> edge base+m, one
// coalesced uint2 load per chunk; e0/len are uniform within the 16-lane row
// group) and broadcast via __shfl. Gathers issue in batches of 8 per lane
// (8 x dwordx4 in flight) -> meta load is off the per-edge critical path and
// MLP doubles vs the round-2 version. Masked slots clamp to last edge
// (weight 0 -> L1-hot re-read). No early returns (callers barrier after).
// ---------------------------------------------------------------------------
template <bool SELF>
__device__ __forceinline__ float spmm_rows(
    const uint4* __restrict__ S4, const int* __restrict__ row_ptr,
    const uint2* __restrict__ ew, const float* __restrict__ ck,
    int r, int n, int lane, float acc[8]) {
  const int m = lane & 15;
  const int g16 = lane & 48;  // base lane of my 16-lane row group
  const int rr = r < n ? r : n - 1;
  const int e0 = row_ptr[rr];
  int len = row_ptr[rr + 1] - e0;
  if (r >= n) len = 0;
  int mx = len;
  mx = max(mx, __shfl_xor(mx, 16));
  mx = max(mx, __shfl_xor(mx, 32));  // wave-uniform
  const int lastOff = len > 0 ? len - 1 : 0;

#pragma unroll
  for (int j = 0; j < 8; ++j) acc[j] = 0.f;
  float ws = 0.f;

  for (int base = 0; base < mx; base += 16) {
    const int mo = base + m;
    const uint2 mym = ew[e0 + (mo < len ? mo : lastOff)];
    const float myw = (mo < len) ? __uint_as_float(mym.y) : 0.f;
#pragma unroll
    for (int h = 0; h < 2; ++h) {
      if (base + h * 8 >= mx) break;  // wave-uniform
      uint4 gv[8];
      float wv[8];
#pragma unroll
      for (int u = 0; u < 8; ++u) {
        const int src = g16 + h * 8 + u;
        const uint cidx = (uint)__shfl((int)mym.x, src);
        wv[u] = __shfl(myw, src);
        gv[u] = S4[(size_t)cidx * 16 + m];
      }
#pragma unroll
      for (int u = 0; u < 8; ++u) {
        const float w = wv[u];
        ws += w;
        acc[0] = fmaf(w, bflo(gv[u].x), acc[0]);
        acc[1] = fmaf(w, bfhi(gv[u].x), acc[1]);
        acc[2] = fmaf(w, bflo(gv[u].y), acc[2]);
        acc[3] = fmaf(w, bfhi(gv[u].y), acc[3]);
        acc[4] = fmaf(w, bflo(gv[u].z), acc[4]);
        acc[5] = fmaf(w, bfhi(gv[u].z), acc[5]);
        acc[6] = fmaf(w, bflo(gv[u].w), acc[6]);
        acc[7] = fmaf(w, bfhi(gv[u].w), acc[7]);
      }
    }
  }

  if (SELF && r < n) {
    uint4 us = S4[(size_t)rr * 16 + m];
    float cp = ck[rr] + 1.0f;
    acc[0] = fmaf(cp, bflo(us.x), acc[0]);
    acc[1] = fmaf(cp, bfhi(us.x), acc[1]);
    acc[2] = fmaf(cp, bflo(us.y), acc[2]);
    acc[3] = fmaf(cp, bfhi(us.y), acc[3]);
    acc[4] = fmaf(cp, bflo(us.z), acc[4]);
    acc[5] = fmaf(cp, bfhi(us.z), acc[5]);
    acc[6] = fmaf(cp, bflo(us.w), acc[6]);
    acc[7] = fmaf(cp, bfhi(us.w), acc[7]);
  }
  return ws;
}

__device__ __forceinline__ uint4 pack_acc(const float acc[8]) {
  uint4 o;
  o.x = (uint)f2bf(acc[0]) | ((uint)f2bf(acc[1]) << 16);
  o.y = (uint)f2bf(acc[2]) | ((uint)f2bf(acc[3]) << 16);
  o.z = (uint)f2bf(acc[4]) | ((uint)f2bf(acc[5]) << 16);
  o.w = (uint)f2bf(acc[6]) | ((uint)f2bf(acc[7]) << 16);
  return o;
}

// ---------------------------------------------------------------------------
// Fused K2: spmm1 (16 rows/block via LDS) + GEMM1 + tanh, LDS-staged
// coalesced y1 writes. Saves the aggbf/rs1 global round trip.
// ---------------------------------------------------------------------------
__global__ __launch_bounds__(256) void spmm_gemm1_kernel(
    const ushort* __restrict__ src, const int* __restrict__ row_ptr,
    const uint2* __restrict__ ew, const ushort* __restrict__ Bf,
    const float* __restrict__ bnb, const float* __restrict__ b1,
    ushort* __restrict__ y1, int n) {
  __shared__ ushort aggT[16 * AGG_S];
  __shared__ ushort y1T[16 * AGG_S];
  __shared__ float rsL[16];

  const int tid = threadIdx.x;
  const int wave = tid >> 6, lane = tid & 63;
  const int g = lane >> 4, m = lane & 15;
  const int rloc = wave * 4 + g;
  const int r = blockIdx.x * 16 + rloc;

  // ---- phase A: spmm into registers, stage bf16 tile in LDS ----
  float acc[8];
  float ws = spmm_rows<false>(reinterpret_cast<const uint4*>(src), row_ptr,
                              ew, nullptr, r, n, lane, acc);
  *reinterpret_cast<uint4*>(&aggT[rloc * AGG_S + m * 8]) = pack_acc(acc);
  if (m == 0) rsL[rloc] = ws;
  __syncthreads();

  // ---- phase B: 16x128 @ 128x128 MFMA; wave handles nt = {2w, 2w+1} ----
  const bf16x8* Bv = reinterpret_cast<const bf16x8*>(Bf);
  bf16x8 af[4];
#pragma unroll
  for (int kc = 0; kc < 4; ++kc)
    af[kc] = *reinterpret_cast<const bf16x8*>(&aggT[m * AGG_S + kc * 32 + g * 8]);

  f32x4 acc2[2];
  acc2[0] = (f32x4){0.f, 0.f, 0.f, 0.f};
  acc2[1] = (f32x4){0.f, 0.f, 0.f, 0.f};
  const int nt0 = wave * 2;
#pragma unroll
  for (int kc = 0; kc < 4; ++kc) {
#pragma unroll
    for (int t = 0; t < 2; ++t) {
      bf16x8 b = Bv[(kc * 8 + nt0 + t) * 64 + lane];
      acc2[t] = __builtin_amdgcn_mfma_f32_16x16x32_bf16(b, af[kc], acc2[t], 0, 0, 0);
    }
  }

  const float rs = rsL[m];
#pragma unroll
  for (int t = 0; t < 2; ++t) {
    const int c = (nt0 + t) * 16 + g * 4;
    const float4 bn = *reinterpret_cast<const float4*>(&bnb[c]);
    const float4 bb = *reinterpret_cast<const float4*>(&b1[c]);
    ushort4 ov;
    ov.x = f2bf(tanhf(acc2[t][0] + rs * bn.x + bb.x));
    ov.y = f2bf(tanhf(acc2[t][1] + rs * bn.y + bb.y));
    ov.z = f2bf(tanhf(acc2[t][2] + rs * bn.z + bb.z));
    ov.w = f2bf(tanhf(acc2[t][3] + rs * bn.w + bb.w));
    *reinterpret_cast<ushort4*>(&y1T[m * AGG_S + c]) = ov;
  }
  __syncthreads();

  // ---- coalesced copy: 16 rows x 256 B = 4 KB, 1 uint4 per thread ----
  const int row = tid >> 4, col = tid & 15;
  uint4 v = *reinterpret_cast<const uint4*>(&y1T[row * AGG_S + col * 8]);
  const size_t gi = (size_t)blockIdx.x * 256 + tid;
  if ((int)(gi >> 4) < n) reinterpret_cast<uint4*>(y1)[gi] = v;
}

// ---------------------------------------------------------------------------
// Fused K3: spmm2(+self) + GEMM2 + bias + tri-L2-normalize + coalesced out.
// Cross-wave row norms via LDS partials; out staged in LDS (aliased over
// aggT: all aggT reads complete before the sp-barrier) and streamed out as
// linear float4 (1 KB/instr) instead of 16 B stores at 1536 B stride.
// ---------------------------------------------------------------------------
__global__ __launch_bounds__(256) void spmm_gemm2_kernel(
    const ushort* __restrict__ src /*y1bf*/, const int* __restrict__ row_ptr,
    const uint2* __restrict__ ew, const ushort* __restrict__ Bf,
    const float* __restrict__ shd, const float* __restrict__ bd,
    const float* __restrict__ ck, const float* __restrict__ x,
    float* __restrict__ out, int n) {
  __shared__ __align__(16) char smemRaw[16 * OUT_S * 4];  // outT / aggT alias
  __shared__ float rsL[16];
  __shared__ float sp0[4][16], sp1[4][16], sp2[4][16];
  ushort* aggT = reinterpret_cast<ushort*>(smemRaw);
  float* outT = reinterpret_cast<float*>(smemRaw);

  const int tid = threadIdx.x;
  const int wave = tid >> 6, lane = tid & 63;
  const int g = lane >> 4, m = lane & 15;
  const int rloc = wave * 4 + g;
  const int r = blockIdx.x * 16 + rloc;

  // ---- phase A: spmm with self term ----
  float acc[8];
  float ws = spmm_rows<true>(reinterpret_cast<const uint4*>(src), row_ptr,
                             ew, ck, r, n, lane, acc);
  *reinterpret_cast<uint4*>(&aggT[rloc * AGG_S + m * 8]) = pack_acc(acc);
  if (m == 0) rsL[rloc] = ws;
  __syncthreads();

  // ---- phase B: GEMM; lane (g,m) owns row m, cols {nt0,nt0+1}*16+g*4 ----
  const bf16x8* Bv = reinterpret_cast<const bf16x8*>(Bf);
  bf16x8 af[4];
#pragma unroll
  for (int kc = 0; kc < 4; ++kc)
    af[kc] = *reinterpret_cast<const bf16x8*>(&aggT[m * AGG_S + kc * 32 + g * 8]);

  f32x4 acc2[2];
  acc2[0] = (f32x4){0.f, 0.f, 0.f, 0.f};
  acc2[1] = (f32x4){0.f, 0.f, 0.f, 0.f};
  const int nt0 = wave * 2;
#pragma unroll
  for (int kc = 0; kc < 4; ++kc) {
#pragma unroll
    for (int t = 0; t < 2; ++t) {
      bf16x8 b = Bv[(kc * 8 + nt0 + t) * 64 + lane];
      acc2[t] = __builtin_amdgcn_mfma_f32_16x16x32_bf16(b, af[kc], acc2[t], 0, 0, 0);
    }
  }

  // x / y1 col-slices: wave w covers cols w*32..w*32+31 of every row.
  const int rm = min(blockIdx.x * 16 + m, n - 1);
  const int c0 = wave * 32 + g * 8;
  const float4 xv0 = *reinterpret_cast<const float4*>(&x[(size_t)rm * D + c0]);
  const float4 xv1 = *reinterpret_cast<const float4*>(&x[(size_t)rm * D + c0 + 4]);
  const uint4 yv = *reinterpret_cast<const uint4*>(&src[(size_t)rm * D + c0]);
  const float ya = bflo(yv.x), yb = bfhi(yv.x), yc = bflo(yv.y), yd = bfhi(yv.y);
  const float ye = bflo(yv.z), yf = bfhi(yv.z), yg = bflo(yv.w), yh = bfhi(yv.w);

  float s0p = xv0.x * xv0.x + xv0.y * xv0.y + xv0.z * xv0.z + xv0.w * xv0.w +
              xv1.x * xv1.x + xv1.y * xv1.y + xv1.z * xv1.z + xv1.w * xv1.w;
  float s1p = ya * ya + yb * yb + yc * yc + yd * yd +
              ye * ye + yf * yf + yg * yg + yh * yh;

  const float rbias = rsL[m] + ck[rm] + 1.0f;
  float s2p = 0.f;
#pragma unroll
  for (int t = 0; t < 2; ++t) {
    const int c = (nt0 + t) * 16 + g * 4;
    const float4 sh = *reinterpret_cast<const float4*>(&shd[c]);
    const float4 bb = *reinterpret_cast<const float4*>(&bd[c]);
    acc2[t][0] += rbias * sh.x + bb.x;
    acc2[t][1] += rbias * sh.y + bb.y;
    acc2[t][2] += rbias * sh.z + bb.z;
    acc2[t][3] += rbias * sh.w + bb.w;
    s2p += acc2[t][0] * acc2[t][0] + acc2[t][1] * acc2[t][1] +
           acc2[t][2] * acc2[t][2] + acc2[t][3] * acc2[t][3];
  }

  // reduce over the 4 g-groups (same row m) within the wave
  s0p += __shfl_xor(s0p, 16); s0p += __shfl_xor(s0p, 32);
  s1p += __shfl_xor(s1p, 16); s1p += __shfl_xor(s1p, 32);
  s2p += __shfl_xor(s2p, 16); s2p += __shfl_xor(s2p, 32);
  if (lane < 16) { sp0[wave][lane] = s0p; sp1[wave][lane] = s1p; sp2[wave][lane] = s2p; }
  __syncthreads();  // also separates all aggT reads from outT writes (alias)

  const float s0 = sp0[0][m] + sp0[1][m] + sp0[2][m] + sp0[3][m];
  const float s1 = sp1[0][m] + sp1[1][m] + sp1[2][m] + sp1[3][m];
  const float s2 = sp2[0][m] + sp2[1][m] + sp2[2][m] + sp2[3][m];
  const float i0 = 1.0f / sqrtf(fmaxf(s0, L2_EPS));
  const float i1 = 1.0f / sqrtf(fmaxf(s1, L2_EPS));
  const float i2 = 1.0f / sqrtf(fmaxf(s2, L2_EPS));
  const float tot = s0 * i0 * i0 + s1 * i1 * i1 + s2 * i2 * i2;
  const float sc = 1.0f / sqrtf(fmaxf(tot, L2_EPS));
  const float f0 = i0 * sc, f1 = i1 * sc, f2 = i2 * sc;

  // ---- stage normalized row into outT ----
  float* orow = &outT[m * OUT_S];
  *reinterpret_cast<float4*>(&orow[c0]) =
      make_float4(xv0.x * f0, xv0.y * f0, xv0.z * f0, xv0.w * f0);
  *reinterpret_cast<float4*>(&orow[c0 + 4]) =
      make_float4(xv1.x * f0, xv1.y * f0, xv1.z * f0, xv1.w * f0);
  *reinterpret_cast<float4*>(&orow[128 + c0]) =
      make_float4(ya * f1, yb * f1, yc * f1, yd * f1);
  *reinterpret_cast<float4*>(&orow[128 + c0 + 4]) =
      make_float4(ye * f1, yf * f1, yg * f1, yh * f1);
#pragma unroll
  for (int t = 0; t < 2; ++t) {
    const int c = (nt0 + t) * 16 + g * 4;
    *reinterpret_cast<float4*>(&orow[256 + c]) =
        make_float4(acc2[t][0] * f2, acc2[t][1] * f2, acc2[t][2] * f2, acc2[t][3] * f2);
  }
  __syncthreads();

  // ---- coalesced copy: 16 rows x 1536 B; 6 x (256 threads x float4) ----
#pragma unroll
  for (int it = 0; it < 6; ++it) {
    const int idx = it * 256 + tid;        // 0..1535
    const int rw = idx / 96, cc = idx % 96;
    float4 v = *reinterpret_cast<const float4*>(&outT[rw * OUT_S + cc * 4]);
    const int gr = blockIdx.x * 16 + rw;
    if (gr < n) reinterpret_cast<float4*>(out)[(size_t)gr * 96 + cc] = v;
  }
}

// ---------------------------------------------------------------------------
extern "C" void kernel_launch(void* const* d_in, const int* in_sizes, int n_in,
                              void* d_out, int out_size, void* d_ws, size_t ws_size,
                              hipStream_t stream) {
  const float* x      = (const float*)d_in[0];
  const int*   rows   = (const int*)d_in[1];
  const int*   cols   = (const int*)d_in[2];
  const float* adj    = (const float*)d_in[3];
  const int*   rel    = (const int*)d_in[4];
  const float* gamma1 = (const float*)d_in[5];
  const float* beta1  = (const float*)d_in[6];
  const float* mean1  = (const float*)d_in[7];
  const float* var1   = (const float*)d_in[8];
  const float* W1     = (const float*)d_in[9];
  const float* b1     = (const float*)d_in[10];
  const float* gamma2 = (const float*)d_in[11];
  const float* beta2  = (const float*)d_in[12];
  const float* mean2  = (const float*)d_in[13];
  const float* var2   = (const float*)d_in[14];
  const float* relc   = (const float*)d_in[15];
  const float* ck     = (const float*)d_in[16];
  const float* Wd     = (const float*)d_in[17];
  const float* bd     = (const float*)d_in[18];
  float* out = (float*)d_out;

  const int n = in_sizes[0] / D;
  const int e = in_sizes[1];
  size_t nd = (size_t)n * D;

  char* p = (char*)d_ws;
  ushort* xbf   = (ushort*)p; p += nd * 2;
  ushort* y1bf  = (ushort*)p; p += nd * 2;
  ushort* Bf1   = (ushort*)p; p += 32768;
  ushort* Bf2   = (ushort*)p; p += 32768;
  float*  bnb   = (float*)p;  p += 512;
  float*  shd   = (float*)p;  p += 512;
  p = (char*)(((uintptr_t)p + 15) & ~(uintptr_t)15);
  uint2* ew1    = (uint2*)p;  p += (size_t)(e + 1) * 8;
  uint2* ew2    = (uint2*)p;  p += (size_t)(e + 1) * 8;
  int* row_ptr  = (int*)p;    p += (size_t)(n + 1) * 4;

  const int n4 = (int)(nd / 4);
  const int nbConv = (n4 + 255) / 256;
  const int nbRp = (n + 1 + 255) / 256;
  const int nbEw = (e + 1 + 255) / 256;
  const int nbPrep = nbConv + nbRp + 18 + nbEw;

  prep_kernel<<<nbPrep, 256, 0, stream>>>(
      x, xbf, n4, rows, row_ptr, n, e,
      W1, gamma1, var1, Bf1, Wd, gamma2, var2, Bf2,
      beta1, mean1, bnb, beta2, mean2, shd,
      cols, adj, rel, relc, ew1, ew2, nbConv, nbRp);

  const int fblocks = (n + 15) / 16;
  spmm_gemm1_kernel<<<fblocks, 256, 0, stream>>>(
      xbf, row_ptr, ew1, Bf1, bnb, b1, y1bf, n);
  spmm_gemm2_kernel<<<fblocks, 256, 0, stream>>>(
      y1bf, row_ptr, ew2, Bf2, shd, bd, ck, x, out, n);
}